// Round 16
// baseline (1367.423 us; speedup 1.0000x reference)
//
#include <hip/hip_runtime.h>
#include <hip/hip_bf16.h>
#include <math.h>

#define TT 128
#define NN 64
#define HH 1024
#define AA 16
#define G3 3072          /* 3*HH */
#define NC 6144          /* combined gi cols */
#define PK 1088          /* padded policy K (1040 -> 1088 = 17*64), zero tail */
#define WLDS_STRIDE 1032 /* LDS stride for persistent weight tile */
#define GISL 3072        /* gi2 floats per (colblock, t): 64 rows * 48 */

#define PD_OFF  0
#define POL_OFF (TT*NN*AA)                  /* 131072 */
#define HXS_OFF (POL_OFF + TT*NN*HH)        /* 8519680 */

typedef __attribute__((ext_vector_type(8))) short short8;
typedef __attribute__((ext_vector_type(4))) float f32x4;

// ---- persistent device buffers (fully rewritten every call) ----
__device__ __align__(16) __hip_bfloat16 g_c_bf[TT*NN*HH];
__device__ __align__(16) __hip_bfloat16 g_wihc_bf[NC*HH];
__device__ __align__(16) __hip_bfloat16 g_pw1_bf[HH*PK];
__device__ __align__(16) __hip_bfloat16 g_pw2_bf[AA*HH];
__device__ float g_gi2[(size_t)2*64*TT*GISL];                   // 201 MB, consumer-contiguous
__device__ float g_h[NN*HH];
__device__ float g_pol[NN*HH];
__device__ __align__(16) __hip_bfloat16 g_pin_all[(size_t)(TT+1)*NN*PK];  // [h(t-1)*m_t | a_t*m_t | 0]
__device__ __align__(16) __hip_bfloat16 g_polm_all[(size_t)(TT+1)*NN*HH]; // pol(t-1)*m_t
__device__ __align__(16) __hip_bfloat16 g_ph_all[TT*NN*HH];      // tanh(policy hidden), bf16

// packed arrival flags (scan) + gi-slab / pol-bm production counters
__device__ __align__(256) unsigned g_flagsA[2][64];
__device__ __align__(256) unsigned g_gi_cnt[64];                 // slab bm ready when == 48
__device__ __align__(256) unsigned g_pol_cnt[64];                // ph bm ready when == 8

__device__ __forceinline__ float sigmoidf_(float x) { return 1.0f / (1.0f + __expf(-x)); }
__device__ __forceinline__ float tanhf_(float x) {
  float e = __expf(2.0f * x);
  return 1.0f - 2.0f / (e + 1.0f);
}

// ---------------- conversions ----------------
__global__ __launch_bounds__(256) void conv_all(
    const float* __restrict__ c, const float* __restrict__ masks, const float* __restrict__ act,
    const float* __restrict__ wih_h, const float* __restrict__ wih_p,
    const float* __restrict__ pw1, const float* __restrict__ pw2)
{
  size_t i = (size_t)blockIdx.x * 256 + threadIdx.x;
  size_t stride = (size_t)gridDim.x * 256;
  for (size_t f = i; f < (size_t)TT*NN*HH; f += stride) g_c_bf[f] = __float2bfloat16(c[f]);
  for (size_t f = i; f < (size_t)G3*HH; f += stride) {
    g_wihc_bf[f]                 = __float2bfloat16(wih_h[f]);
    g_wihc_bf[(size_t)G3*HH + f] = __float2bfloat16(wih_p[f]);
  }
  for (size_t f = i; f < (size_t)HH*PK; f += stride) {
    int o = (int)(f / PK), j = (int)(f % PK);
    g_pw1_bf[f] = (j < HH + AA) ? __float2bfloat16(pw1[(size_t)o*(HH+AA) + j]) : __float2bfloat16(0.0f);
  }
  for (size_t f = i; f < (size_t)AA*HH; f += stride) g_pw2_bf[f] = __float2bfloat16(pw2[f]);
  for (size_t f = i; f < (size_t)TT*NN*(PK-HH); f += stride) {
    int row = (int)(f >> 6), j = (int)(f & 63);
    float v = (j < AA) ? act[(size_t)row*AA + j] * masks[row] : 0.0f;
    g_pin_all[(size_t)row*PK + HH + j] = __float2bfloat16(v);
  }
}

__global__ __launch_bounds__(256) void init_kernel(const float* __restrict__ hxs,
                                                   const float* __restrict__ masks) {
  int f = blockIdx.x * 256 + threadIdx.x;      // NN*HH threads
  int n = f >> 10, j = f & 1023;
  float m0 = masks[n];
  float hv = hxs[n * 2 * HH + j];
  float pv = hxs[n * 2 * HH + HH + j];
  g_h[f] = hv;
  g_pol[f] = pv;
  g_pin_all[(size_t)n * PK + j]  = __float2bfloat16(hv * m0);
  g_polm_all[(size_t)n * HH + j] = __float2bfloat16(pv * m0);
  if (f < 128)
    __hip_atomic_store(&g_flagsA[f >> 6][f & 63], 0u,
                       __ATOMIC_RELAXED, __HIP_MEMORY_SCOPE_AGENT);
  if (f >= 128 && f < 192)
    __hip_atomic_store(&g_gi_cnt[f - 128], 0u,
                       __ATOMIC_RELAXED, __HIP_MEMORY_SCOPE_AGENT);
  if (f >= 192 && f < 256)
    __hip_atomic_store(&g_pol_cnt[f - 192], 0u,
                       __ATOMIC_RELAXED, __HIP_MEMORY_SCOPE_AGENT);
}

// ---------------- fused persistent kernel ----------------
// blocks 0..127:   2-GRU scan; per-group gate->load->MFMA interleave; register-direct publish
// blocks 128..255: producers: 24 gi tiles -> 4 pol_gemm tiles (flag-gated) -> 1 pdist chunk
__global__ __launch_bounds__(256, 1) void fused_scan(
    const float* __restrict__ masks,
    const float* __restrict__ whh_h, const float* __restrict__ whh_p,
    const float* __restrict__ bih_h, const float* __restrict__ bhh_h,
    const float* __restrict__ bih_p, const float* __restrict__ bhh_p,
    const float* __restrict__ pb1, const float* __restrict__ pb2,
    float* __restrict__ out)
{
  extern __shared__ __align__(16) __hip_bfloat16 Dyn[];  // scan: Ws[48][1032]; gemm: As/Bs
  __shared__ float m_lds[TT * NN];                       // 32 KB masks (scan only)
  const int tid = threadIdx.x, l = tid & 63, w = tid >> 6;

  if (blockIdx.x < 128) {
    // ================= scan path =================
    __hip_bfloat16* Ws = Dyn;
    const int gru = blockIdx.x >> 6;
    const int idx = blockIdx.x & 63;
    const int c0  = idx * 16;
    const float* __restrict__ Wf = (gru == 0) ? whh_h : whh_p;

    for (int i = tid; i < TT * NN; i += 256) m_lds[i] = masks[i];

    // stage weights directly from fp32 (convert inline)
    for (int ch = tid; ch < 48 * 128; ch += 256) {
      int row = ch >> 7, ko = (ch & 127) * 8;
      int gate = row >> 4, j = row & 15;
      const float* s = Wf + (size_t)(gate * HH + c0 + j) * HH + ko;
      union { short8 v; __hip_bfloat16 hh[8]; } tmp;
#pragma unroll
      for (int q = 0; q < 8; ++q) tmp.hh[q] = __float2bfloat16(s[q]);
      *(short8*)(&Ws[row * WLDS_STRIDE + ko]) = tmp.v;
    }
    __syncthreads();

    const float* bi = (gru == 0) ? bih_h : bih_p;
    const float* bh = (gru == 0) ? bhh_h : bhh_p;
    const int col = c0 + (l & 15);
    const float bir = bi[col],        bhr = bh[col];
    const float biz = bi[HH + col],   bhz = bh[HH + col];
    const float bin = bi[2*HH + col], bhn = bh[2*HH + col];
    const int rowbase = w * 16 + (l >> 4) * 4;
    const int arow = w * 16 + (l & 15);
    const int lo8 = (l >> 4) * 8;
    const int jj = l & 15;

    float hst[4];
    {
      const float* st0 = (gru == 0) ? g_h : g_pol;
#pragma unroll
      for (int reg = 0; reg < 4; ++reg) hst[reg] = st0[(rowbase + reg) * HH + col];
    }

    // gate gi slab 0, then prefetch gi for t=0
    unsigned gi_ready = 0;
    while (__hip_atomic_load(&g_gi_cnt[0], __ATOMIC_RELAXED,
                             __HIP_MEMORY_SCOPE_AGENT) < 48u) { }
    asm volatile("" ::: "memory");
    gi_ready = 1;
    const float* __restrict__ gib = g_gi2 + (size_t)(gru * 64 + idx) * TT * GISL;
    float gir[4], giz[4], gin[4];
#pragma unroll
    for (int reg = 0; reg < 4; ++reg) {
      const float* gp = gib + (size_t)(rowbase + reg) * 48;
      gir[reg] = gp[jj]; giz[reg] = gp[16 + jj]; gin[reg] = gp[32 + jj];
    }

    const int astr = (gru == 0) ? PK : HH;

    for (int t = 0; t < TT; ++t) {
      const __hip_bfloat16* __restrict__ Ab =
          (gru == 0) ? (g_pin_all + (size_t)t * NN * PK)
                     : (g_polm_all + (size_t)t * NN * HH);
      const __hip_bfloat16* __restrict__ arowp = Ab + (size_t)arow * astr + lo8;

      // ---- per-group gate -> load -> MFMA (laggard latency overlaps ready-group MFMAs)
      unsigned fv = __hip_atomic_load(&g_flagsA[gru][l], __ATOMIC_RELAXED,
                                      __HIP_MEMORY_SCOPE_AGENT);
      unsigned long long rdy = __ballot(fv >= (unsigned)t);
      f32x4 acc0 = {}, acc1 = {}, acc2 = {};
#pragma unroll
      for (int g = 0; g < 8; ++g) {
        while (((rdy >> (g * 8)) & 0xFFull) != 0xFFull) {
          fv = __hip_atomic_load(&g_flagsA[gru][l], __ATOMIC_RELAXED,
                                 __HIP_MEMORY_SCOPE_AGENT);
          rdy = __ballot(fv >= (unsigned)t);
        }
        asm volatile("" ::: "memory");
        short8 av4[4];
#pragma unroll
        for (int q = 0; q < 4; ++q)
          av4[q] = *(const short8*)(arowp + (g * 4 + q) * 32);
#pragma unroll
        for (int q = 0; q < 4; ++q) {
          const int u = g * 4 + q;
          short8 b0  = *(const short8*)(&Ws[( 0 + jj) * WLDS_STRIDE + u * 32 + lo8]);
          short8 b1  = *(const short8*)(&Ws[(16 + jj) * WLDS_STRIDE + u * 32 + lo8]);
          short8 bn2 = *(const short8*)(&Ws[(32 + jj) * WLDS_STRIDE + u * 32 + lo8]);
          acc0 = __builtin_amdgcn_mfma_f32_16x16x32_bf16(av4[q], b0,  acc0, 0, 0, 0);
          acc1 = __builtin_amdgcn_mfma_f32_16x16x32_bf16(av4[q], b1,  acc1, 0, 0, 0);
          acc2 = __builtin_amdgcn_mfma_f32_16x16x32_bf16(av4[q], bn2, acc2, 0, 0, 0);
        }
      }

      // ---- epilogue + register-direct publish (2B agent-scope stores, no LDS repack)
#pragma unroll
      for (int reg = 0; reg < 4; ++reg) {
        int row = rowbase + reg;
        float mk  = m_lds[t * NN + row];
        float mk1 = (t < TT - 1) ? m_lds[(t + 1) * NN + row] : 1.0f;
        float hm = hst[reg] * mk;
        float rg  = sigmoidf_(gir[reg] + acc0[reg] + bir + bhr);
        float z   = sigmoidf_(giz[reg] + acc1[reg] + biz + bhz);
        float nn2 = tanhf_  (gin[reg] + bin + rg * (acc2[reg] + bhn));
        float hv = (1.0f - z) * nn2 + z * hm;
        hst[reg] = hv;
        if (gru == 1) out[POL_OFF + (size_t)(t * NN + row) * HH + col] = hv;
        if (t < TT - 1) {
          __hip_bfloat16 hb = __float2bfloat16(hv * mk1);
          unsigned short us; __builtin_memcpy(&us, &hb, 2);
          unsigned short* dstp = (gru == 0)
              ? (unsigned short*)(g_pin_all + (size_t)(t + 1) * NN * PK + (size_t)row * PK + col)
              : (unsigned short*)(g_polm_all + (size_t)(t + 1) * NN * HH + (size_t)row * HH + col);
          __hip_atomic_store(dstp, us, __ATOMIC_RELAXED, __HIP_MEMORY_SCOPE_AGENT);
        }
      }

      if (t < TT - 1) {
        asm volatile("s_waitcnt vmcnt(0)" ::: "memory");   // own publish drained to L3
        __syncthreads();                                   // all waves drained
        if (tid == 0)
          __hip_atomic_store((unsigned*)&g_flagsA[gru][idx], (unsigned)(t + 1),
                             __ATOMIC_RELAXED, __HIP_MEMORY_SCOPE_AGENT);
        // gi gate (cached-monotonic) + prefetch for t+1 (overlaps others' visibility)
        {
          const unsigned slab = (unsigned)((t + 1) >> 1);
          if (slab >= gi_ready) {
            while (__hip_atomic_load(&g_gi_cnt[slab], __ATOMIC_RELAXED,
                                     __HIP_MEMORY_SCOPE_AGENT) < 48u) { }
            asm volatile("" ::: "memory");
            gi_ready = slab + 1;
          }
          const float* gpt = gib + (size_t)(t + 1) * GISL;
#pragma unroll
          for (int reg = 0; reg < 4; ++reg) {
            const float* gp = gpt + (size_t)(rowbase + reg) * 48;
            gir[reg] = gp[jj]; giz[reg] = gp[16 + jj]; gin[reg] = gp[32 + jj];
          }
        }
      }
    }

    float* stf = (gru == 0) ? g_h : g_pol;
#pragma unroll
    for (int reg = 0; reg < 4; ++reg) stf[(rowbase + reg) * HH + col] = hst[reg];

  } else {
    // ================= producer path =================
    __hip_bfloat16* AsD = Dyn;                  // [2][128*72]
    __hip_bfloat16* BsD = Dyn + 2 * 128 * 72;   // [2][128*72]
    const int roff = (w >> 1) * 64, coff = (w & 1) * 64;
    const int pid = blockIdx.x - 128;

    // ---- phase 1: 24 gi tiles (bm-major) ----
    for (int kt2 = 0; kt2 < 24; ++kt2) {
      const int tile = pid + (kt2 << 7);
      const int bm = tile / 48, bn = tile % 48;
      const __hip_bfloat16* A = g_c_bf    + (size_t)bm * 128 * HH;
      const __hip_bfloat16* B = g_wihc_bf + (size_t)bn * 128 * HH;

      short8 ra[4], rb[4];
#define PG_LOAD(KT, AP, BP, STR) { _Pragma("unroll") for (int q = 0; q < 4; ++q) { \
    int cch = q * 256 + tid; int row = cch >> 3, ko = (cch & 7) * 8; \
    ra[q] = *(const short8*)((AP) + (size_t)row * (STR) + (KT) * 64 + ko); \
    rb[q] = *(const short8*)((BP) + (size_t)row * (STR) + (KT) * 64 + ko); } }
#define PG_STORE(BUF) { _Pragma("unroll") for (int q = 0; q < 4; ++q) { \
    int cch = q * 256 + tid; int row = cch >> 3, ko = (cch & 7) * 8; \
    *(short8*)(AsD + (BUF) * 9216 + row * 72 + ko) = ra[q]; \
    *(short8*)(BsD + (BUF) * 9216 + row * 72 + ko) = rb[q]; } }
#define PG_MMA(BUF) { _Pragma("unroll") for (int ks = 0; ks < 2; ++ks) { \
      short8 a[4], b[4]; \
      _Pragma("unroll") for (int fr = 0; fr < 4; ++fr) \
        a[fr] = *(const short8*)(AsD + (BUF) * 9216 + (roff + fr * 16 + (l & 15)) * 72 + ks * 32 + (l >> 4) * 8); \
      _Pragma("unroll") for (int fc = 0; fc < 4; ++fc) \
        b[fc] = *(const short8*)(BsD + (BUF) * 9216 + (coff + fc * 16 + (l & 15)) * 72 + ks * 32 + (l >> 4) * 8); \
      _Pragma("unroll") for (int fr = 0; fr < 4; ++fr) \
        _Pragma("unroll") for (int fc = 0; fc < 4; ++fc) \
          acc[fr][fc] = __builtin_amdgcn_mfma_f32_16x16x32_bf16(a[fr], b[fc], acc[fr][fc], 0, 0, 0); } }

      __syncthreads();
      PG_LOAD(0, A, B, HH) PG_STORE(0)
      f32x4 acc[4][4] = {};
      for (int kt = 0; kt < 16; ++kt) {
        __syncthreads();
        if (kt < 15) PG_LOAD(kt + 1, A, B, HH)
        PG_MMA(kt & 1)
        if (kt < 15) PG_STORE((kt + 1) & 1)
      }
#pragma unroll
      for (int fr = 0; fr < 4; ++fr)
#pragma unroll
        for (int fc = 0; fc < 4; ++fc) {
          int colg = bn * 128 + coff + fc * 16 + (l & 15);
          int q2 = colg >> 10;
          int gru2 = (q2 >= 3), gate = q2 - 3 * gru2;
          int hcol = colg & 1023, cb = hcol >> 4, j = hcol & 15;
#pragma unroll
          for (int reg = 0; reg < 4; ++reg) {
            int grow = bm * 128 + roff + fr * 16 + (l >> 4) * 4 + reg;
            int tt2 = grow >> 6, n = grow & 63;
            __hip_atomic_store(
                &g_gi2[((size_t)(gru2 * 64 + cb) * TT + tt2) * GISL + n * 48 + gate * 16 + j],
                acc[fr][fc][reg], __ATOMIC_RELAXED, __HIP_MEMORY_SCOPE_AGENT);
          }
        }
      asm volatile("s_waitcnt vmcnt(0)" ::: "memory");
      __syncthreads();
      if (tid == 0)
        __hip_atomic_fetch_add(&g_gi_cnt[bm], 1u,
                               __ATOMIC_RELAXED, __HIP_MEMORY_SCOPE_AGENT);
    }

    // ---- phase 2: 4 pol_gemm tiles, gated on scan flags ----
    for (int k2 = 0; k2 < 4; ++k2) {
      const int tile = (k2 << 7) + pid;        // 0..511
      const int bm = tile >> 3, bn = tile & 7;
      const unsigned need = (unsigned)(2 * bm + 1);
      {
        unsigned fv;
        do {
          fv = __hip_atomic_load(&g_flagsA[0][l], __ATOMIC_RELAXED,
                                 __HIP_MEMORY_SCOPE_AGENT);
        } while (!__all(fv >= need));
        asm volatile("" ::: "memory");
      }
      const __hip_bfloat16* A = g_pin_all + (size_t)bm * 128 * PK;
      const __hip_bfloat16* B = g_pw1_bf  + (size_t)bn * 128 * PK;

      short8 ra[4], rb[4];
      __syncthreads();
      PG_LOAD(0, A, B, PK) PG_STORE(0)
      f32x4 acc[4][4] = {};
      for (int kt = 0; kt < 17; ++kt) {
        __syncthreads();
        if (kt < 16) PG_LOAD(kt + 1, A, B, PK)
        PG_MMA(kt & 1)
        if (kt < 16) PG_STORE((kt + 1) & 1)
      }
#pragma unroll
      for (int fc = 0; fc < 4; ++fc) {
        int colg = bn * 128 + coff + fc * 16 + (l & 15);
        float b1v = pb1[colg];
#pragma unroll
        for (int fr = 0; fr < 4; ++fr)
#pragma unroll
          for (int reg = 0; reg < 4; ++reg) {
            int row = bm * 128 + roff + fr * 16 + (l >> 4) * 4 + reg;
            __hip_bfloat16 hb = __float2bfloat16(tanhf_(acc[fr][fc][reg] + b1v));
            unsigned short us; __builtin_memcpy(&us, &hb, 2);
            __hip_atomic_store((unsigned short*)&g_ph_all[(size_t)row * HH + colg], us,
                               __ATOMIC_RELAXED, __HIP_MEMORY_SCOPE_AGENT);
          }
      }
      asm volatile("s_waitcnt vmcnt(0)" ::: "memory");
      __syncthreads();
      if (tid == 0)
        __hip_atomic_fetch_add(&g_pol_cnt[bm], 1u,
                               __ATOMIC_RELAXED, __HIP_MEMORY_SCOPE_AGENT);
    }

    // ---- phase 3: pdist chunk (64 rows), gated on pol_cnt ----
    {
      const int r0 = pid * 64;
      const int bm2 = pid >> 1;
      while (__hip_atomic_load(&g_pol_cnt[bm2], __ATOMIC_RELAXED,
                               __HIP_MEMORY_SCOPE_AGENT) < 8u) { }
      asm volatile("" ::: "memory");
      f32x4 pa = {};
      const __hip_bfloat16* PH = g_ph_all + (size_t)(r0 + w * 16 + (l & 15)) * HH;
      const __hip_bfloat16* B  = g_pw2_bf + (size_t)(l & 15) * HH;
#pragma unroll 4
      for (int k32 = 0; k32 < 32; ++k32) {
        short8 a = *(const short8*)(PH + k32 * 32 + (l >> 4) * 8);
        short8 b = *(const short8*)(B  + k32 * 32 + (l >> 4) * 8);
        pa = __builtin_amdgcn_mfma_f32_16x16x32_bf16(a, b, pa, 0, 0, 0);
      }
      int o = l & 15;
      float bb = pb2[o];
#pragma unroll
      for (int reg = 0; reg < 4; ++reg) {
        int row = r0 + w * 16 + (l >> 4) * 4 + reg;
        out[PD_OFF + (size_t)row * AA + o] = pa[reg] + bb;
      }
    }
  }
}

// ---------------- final: hxs output ----------------
__global__ __launch_bounds__(256) void final_kernel(float* __restrict__ out) {
  int f = blockIdx.x * 256 + threadIdx.x;   // < 131072
  int n = f >> 11, j = f & 2047;
  out[HXS_OFF + f] = (j < HH) ? g_h[n * HH + j] : g_pol[n * HH + (j - HH)];
}

extern "C" void kernel_launch(void* const* d_in, const int* in_sizes, int n_in,
                              void* d_out, int out_size, void* d_ws, size_t ws_size,
                              hipStream_t stream) {
  const float* c     = (const float*)d_in[0];
  const float* hxs   = (const float*)d_in[1];
  const float* masks = (const float*)d_in[2];
  const float* act   = (const float*)d_in[3];
  const float* wih_h = (const float*)d_in[4];
  const float* whh_h = (const float*)d_in[5];
  const float* bih_h = (const float*)d_in[6];
  const float* bhh_h = (const float*)d_in[7];
  const float* wih_p = (const float*)d_in[8];
  const float* whh_p = (const float*)d_in[9];
  const float* bih_p = (const float*)d_in[10];
  const float* bhh_p = (const float*)d_in[11];
  const float* pw1   = (const float*)d_in[12];
  const float* pb1   = (const float*)d_in[13];
  const float* pw2   = (const float*)d_in[14];
  const float* pb2   = (const float*)d_in[15];
  float* out = (float*)d_out;

  const int dyn_bytes = 48 * WLDS_STRIDE * 2;   // 99072 (>= gemm's 73728)
  (void)hipFuncSetAttribute((const void*)fused_scan,
                            hipFuncAttributeMaxDynamicSharedMemorySize, dyn_bytes);

  conv_all<<<4096, 256, 0, stream>>>(c, masks, act, wih_h, wih_p, pw1, pw2);
  init_kernel<<<256, 256, 0, stream>>>(hxs, masks);
  fused_scan<<<256, 256, dyn_bytes, stream>>>(masks, whh_h, whh_p,
                                              bih_h, bhh_h, bih_p, bhh_p,
                                              pb1, pb2, out);
  final_kernel<<<512, 256, 0, stream>>>(out);
}

// Round 17
// 1066.860 us; speedup vs baseline: 1.2817x; 1.2817x over previous
//
#include <hip/hip_runtime.h>
#include <hip/hip_bf16.h>
#include <math.h>

#define TT 128
#define NN 64
#define HH 1024
#define AA 16
#define G3 3072          /* 3*HH */
#define NC 6144          /* combined gi cols */
#define PK 1088          /* padded policy K (1040 -> 1088 = 17*64), zero tail */
#define WLDS_STRIDE 1032 /* LDS stride for persistent weight tile */
#define GISL 3072        /* gi2 floats per (colblock, t): 64 rows * 48 */

#define PD_OFF  0
#define POL_OFF (TT*NN*AA)                  /* 131072 */
#define HXS_OFF (POL_OFF + TT*NN*HH)        /* 8519680 */

typedef __attribute__((ext_vector_type(8))) short short8;
typedef __attribute__((ext_vector_type(4))) float f32x4;

// ---- persistent device buffers (fully rewritten every call) ----
__device__ __align__(16) __hip_bfloat16 g_c_bf[TT*NN*HH];
__device__ __align__(16) __hip_bfloat16 g_wihc_bf[NC*HH];
__device__ __align__(16) __hip_bfloat16 g_pw1_bf[HH*PK];
__device__ __align__(16) __hip_bfloat16 g_pw2_bf[AA*HH];
__device__ float g_gi2[(size_t)2*64*TT*GISL];                   // 201 MB, consumer-contiguous
__device__ float g_h[NN*HH];
__device__ float g_pol[NN*HH];
__device__ __align__(16) __hip_bfloat16 g_pin_all[(size_t)(TT+1)*NN*PK];  // [h(t-1)*m_t | a_t*m_t | 0]
__device__ __align__(16) __hip_bfloat16 g_polm_all[(size_t)(TT+1)*NN*HH]; // pol(t-1)*m_t
__device__ __align__(16) __hip_bfloat16 g_ph_all[TT*NN*HH];      // tanh(policy hidden), bf16

// packed arrival flags (scan) + gi-slab / pol-bm production counters
__device__ __align__(256) unsigned g_flagsA[2][64];
__device__ __align__(256) unsigned g_gi_cnt[64];                 // slab bm ready when == 48
__device__ __align__(256) unsigned g_pol_cnt[64];                // ph bm ready when == 8

__device__ __forceinline__ float sigmoidf_(float x) { return 1.0f / (1.0f + __expf(-x)); }
__device__ __forceinline__ float tanhf_(float x) {
  float e = __expf(2.0f * x);
  return 1.0f - 2.0f / (e + 1.0f);
}

// ---------------- conversions (whh no longer converted here) ----------------
__global__ __launch_bounds__(256) void conv_all(
    const float* __restrict__ c, const float* __restrict__ masks, const float* __restrict__ act,
    const float* __restrict__ wih_h, const float* __restrict__ wih_p,
    const float* __restrict__ pw1, const float* __restrict__ pw2)
{
  size_t i = (size_t)blockIdx.x * 256 + threadIdx.x;
  size_t stride = (size_t)gridDim.x * 256;
  for (size_t f = i; f < (size_t)TT*NN*HH; f += stride) g_c_bf[f] = __float2bfloat16(c[f]);
  for (size_t f = i; f < (size_t)G3*HH; f += stride) {
    g_wihc_bf[f]                 = __float2bfloat16(wih_h[f]);
    g_wihc_bf[(size_t)G3*HH + f] = __float2bfloat16(wih_p[f]);
  }
  for (size_t f = i; f < (size_t)HH*PK; f += stride) {
    int o = (int)(f / PK), j = (int)(f % PK);
    g_pw1_bf[f] = (j < HH + AA) ? __float2bfloat16(pw1[(size_t)o*(HH+AA) + j]) : __float2bfloat16(0.0f);
  }
  for (size_t f = i; f < (size_t)AA*HH; f += stride) g_pw2_bf[f] = __float2bfloat16(pw2[f]);
  for (size_t f = i; f < (size_t)TT*NN*(PK-HH); f += stride) {
    int row = (int)(f >> 6), j = (int)(f & 63);
    float v = (j < AA) ? act[(size_t)row*AA + j] * masks[row] : 0.0f;
    g_pin_all[(size_t)row*PK + HH + j] = __float2bfloat16(v);
  }
}

__global__ __launch_bounds__(256) void init_kernel(const float* __restrict__ hxs,
                                                   const float* __restrict__ masks) {
  int f = blockIdx.x * 256 + threadIdx.x;      // NN*HH threads
  int n = f >> 10, j = f & 1023;
  float m0 = masks[n];
  float hv = hxs[n * 2 * HH + j];
  float pv = hxs[n * 2 * HH + HH + j];
  g_h[f] = hv;
  g_pol[f] = pv;
  g_pin_all[(size_t)n * PK + j]  = __float2bfloat16(hv * m0);
  g_polm_all[(size_t)n * HH + j] = __float2bfloat16(pv * m0);
  if (f < 128)
    __hip_atomic_store(&g_flagsA[f >> 6][f & 63], 0u,
                       __ATOMIC_RELAXED, __HIP_MEMORY_SCOPE_AGENT);
  if (f >= 128 && f < 192)
    __hip_atomic_store(&g_gi_cnt[f - 128], 0u,
                       __ATOMIC_RELAXED, __HIP_MEMORY_SCOPE_AGENT);
  if (f >= 192 && f < 256)
    __hip_atomic_store(&g_pol_cnt[f - 192], 0u,
                       __ATOMIC_RELAXED, __HIP_MEMORY_SCOPE_AGENT);
}

// ---------------- fused persistent kernel ----------------
// blocks 0..127:   2-GRU scan with ready-ballot chunk gating (no end-of-step barrier)
// blocks 128..255: producers: 24 gi tiles -> 4 pol_gemm tiles (flag-gated) -> 1 pdist chunk
__global__ __launch_bounds__(256, 1) void fused_scan(
    const float* __restrict__ masks,
    const float* __restrict__ whh_h, const float* __restrict__ whh_p,
    const float* __restrict__ bih_h, const float* __restrict__ bhh_h,
    const float* __restrict__ bih_p, const float* __restrict__ bhh_p,
    const float* __restrict__ pb1, const float* __restrict__ pb2,
    float* __restrict__ out)
{
  extern __shared__ __align__(16) __hip_bfloat16 Dyn[];  // scan: Ws[48][1032]; gemm: As/Bs
  __shared__ float m_lds[TT * NN];                       // 32 KB masks (scan only)
  __shared__ __align__(8) __hip_bfloat16 sL[NN * 16];    // 2 KB repack (scan only)
  const int tid = threadIdx.x, l = tid & 63, w = tid >> 6;

  if (blockIdx.x < 128) {
    // ================= scan path =================
    __hip_bfloat16* Ws = Dyn;
    const int gru = blockIdx.x >> 6;
    const int idx = blockIdx.x & 63;
    const int c0  = idx * 16;
    const float* __restrict__ Wf = (gru == 0) ? whh_h : whh_p;

    for (int i = tid; i < TT * NN; i += 256) m_lds[i] = masks[i];

    // stage weights directly from fp32 (convert inline)
    for (int ch = tid; ch < 48 * 128; ch += 256) {
      int row = ch >> 7, ko = (ch & 127) * 8;
      int gate = row >> 4, j = row & 15;
      const float* s = Wf + (size_t)(gate * HH + c0 + j) * HH + ko;
      union { short8 v; __hip_bfloat16 hh[8]; } tmp;
#pragma unroll
      for (int q = 0; q < 8; ++q) tmp.hh[q] = __float2bfloat16(s[q]);
      *(short8*)(&Ws[row * WLDS_STRIDE + ko]) = tmp.v;
    }
    __syncthreads();

    const float* bi = (gru == 0) ? bih_h : bih_p;
    const float* bh = (gru == 0) ? bhh_h : bhh_p;
    const int col = c0 + (l & 15);
    const float bir = bi[col],        bhr = bh[col];
    const float biz = bi[HH + col],   bhz = bh[HH + col];
    const float bin = bi[2*HH + col], bhn = bh[2*HH + col];
    const int rowbase = w * 16 + (l >> 4) * 4;
    const int arow = w * 16 + (l & 15);
    const int lo8 = (l >> 4) * 8;
    const int jj = l & 15;

    float hst[4];
    {
      const float* st0 = (gru == 0) ? g_h : g_pol;
#pragma unroll
      for (int reg = 0; reg < 4; ++reg) hst[reg] = st0[(rowbase + reg) * HH + col];
    }

    // gate gi slab 0, then prefetch gi for t=0
    unsigned gi_ready = 0;   // highest slab known complete + 1
    while (__hip_atomic_load(&g_gi_cnt[0], __ATOMIC_RELAXED,
                             __HIP_MEMORY_SCOPE_AGENT) < 48u) { }
    asm volatile("" ::: "memory");
    gi_ready = 1;
    const float* __restrict__ gib = g_gi2 + (size_t)(gru * 64 + idx) * TT * GISL;
    float gir[4], giz[4], gin[4];
#pragma unroll
    for (int reg = 0; reg < 4; ++reg) {
      const float* gp = gib + (size_t)(rowbase + reg) * 48;
      gir[reg] = gp[jj]; giz[reg] = gp[16 + jj]; gin[reg] = gp[32 + jj];
    }

    const int astr = (gru == 0) ? PK : HH;

    for (int t = 0; t < TT; ++t) {
      const __hip_bfloat16* __restrict__ Ab =
          (gru == 0) ? (g_pin_all + (size_t)t * NN * PK)
                     : (g_polm_all + (size_t)t * NN * HH);
      const __hip_bfloat16* __restrict__ arowp = Ab + (size_t)arow * astr + lo8;

      // ---- ready-ballot chunk gating: group g = producer blocks 8g..8g+7 ----
      unsigned fv = __hip_atomic_load(&g_flagsA[gru][l], __ATOMIC_RELAXED,
                                      __HIP_MEMORY_SCOPE_AGENT);
      unsigned long long rdy = __ballot(fv >= (unsigned)t);
      short8 av[32];
#pragma unroll
      for (int g = 0; g < 8; ++g) {
        while (((rdy >> (g * 8)) & 0xFFull) != 0xFFull) {
          fv = __hip_atomic_load(&g_flagsA[gru][l], __ATOMIC_RELAXED,
                                 __HIP_MEMORY_SCOPE_AGENT);
          rdy = __ballot(fv >= (unsigned)t);
        }
        asm volatile("" ::: "memory");
#pragma unroll
        for (int q = 0; q < 4; ++q)
          av[g * 4 + q] = *(const short8*)(arowp + (g * 4 + q) * 32);
      }

      f32x4 acc0 = {}, acc1 = {}, acc2 = {};
#pragma unroll
      for (int u = 0; u < 32; ++u) {
        short8 b0  = *(const short8*)(&Ws[( 0 + jj) * WLDS_STRIDE + u * 32 + lo8]);
        short8 b1  = *(const short8*)(&Ws[(16 + jj) * WLDS_STRIDE + u * 32 + lo8]);
        short8 bn2 = *(const short8*)(&Ws[(32 + jj) * WLDS_STRIDE + u * 32 + lo8]);
        acc0 = __builtin_amdgcn_mfma_f32_16x16x32_bf16(av[u], b0,  acc0, 0, 0, 0);
        acc1 = __builtin_amdgcn_mfma_f32_16x16x32_bf16(av[u], b1,  acc1, 0, 0, 0);
        acc2 = __builtin_amdgcn_mfma_f32_16x16x32_bf16(av[u], bn2, acc2, 0, 0, 0);
      }

      float hv_out[4];
#pragma unroll
      for (int reg = 0; reg < 4; ++reg) {
        int row = rowbase + reg;
        float mk  = m_lds[t * NN + row];
        float mk1 = (t < TT - 1) ? m_lds[(t + 1) * NN + row] : 1.0f;
        float hm = hst[reg] * mk;
        float rg  = sigmoidf_(gir[reg] + acc0[reg] + bir + bhr);
        float z   = sigmoidf_(giz[reg] + acc1[reg] + biz + bhz);
        float nn2 = tanhf_  (gin[reg] + bin + rg * (acc2[reg] + bhn));
        float hv = (1.0f - z) * nn2 + z * hm;
        hst[reg] = hv;
        hv_out[reg] = hv;
        sL[row * 16 + jj] = __float2bfloat16(hv * mk1);
      }

      __syncthreads();   // sL complete
      {
        int rr = tid >> 2, cc = tid & 3;
        unsigned long long v = *(const unsigned long long*)(&sL[rr * 16 + cc * 4]);
        __hip_bfloat16* dstp = (gru == 0)
            ? (g_pin_all + (size_t)(t + 1) * NN * PK + (size_t)rr * PK + c0 + cc * 4)
            : (g_polm_all + (size_t)(t + 1) * NN * HH + (size_t)rr * HH + c0 + cc * 4);
        __hip_atomic_store((unsigned long long*)dstp, v,
                           __ATOMIC_RELAXED, __HIP_MEMORY_SCOPE_AGENT);
      }
      asm volatile("s_waitcnt vmcnt(0)" ::: "memory");   // publish drained to L3
      __syncthreads();                                   // all waves drained + sL reads done

      if (t < TT - 1) {
        if (tid == 0)
          __hip_atomic_store((unsigned*)&g_flagsA[gru][idx], (unsigned)(t + 1),
                             __ATOMIC_RELAXED, __HIP_MEMORY_SCOPE_AGENT);
        if (gru == 1) {
#pragma unroll
          for (int reg = 0; reg < 4; ++reg)
            out[POL_OFF + (size_t)(t * NN + rowbase + reg) * HH + col] = hv_out[reg];
        }
        // gi gate (cached-monotonic) + prefetch for t+1
        {
          const unsigned slab = (unsigned)((t + 1) >> 1);
          if (slab >= gi_ready) {
            while (__hip_atomic_load(&g_gi_cnt[slab], __ATOMIC_RELAXED,
                                     __HIP_MEMORY_SCOPE_AGENT) < 48u) { }
            asm volatile("" ::: "memory");
            gi_ready = slab + 1;
          }
          const float* gpt = gib + (size_t)(t + 1) * GISL;
#pragma unroll
          for (int reg = 0; reg < 4; ++reg) {
            const float* gp = gpt + (size_t)(rowbase + reg) * 48;
            gir[reg] = gp[jj]; giz[reg] = gp[16 + jj]; gin[reg] = gp[32 + jj];
          }
        }
      } else {
        if (gru == 1) {
#pragma unroll
          for (int reg = 0; reg < 4; ++reg)
            out[POL_OFF + (size_t)(t * NN + rowbase + reg) * HH + col] = hv_out[reg];
        }
      }
    }

    float* stf = (gru == 0) ? g_h : g_pol;
#pragma unroll
    for (int reg = 0; reg < 4; ++reg) stf[(rowbase + reg) * HH + col] = hst[reg];

  } else {
    // ================= producer path =================
    __hip_bfloat16* AsD = Dyn;                  // [2][128*72]
    __hip_bfloat16* BsD = Dyn + 2 * 128 * 72;   // [2][128*72]
    const int roff = (w >> 1) * 64, coff = (w & 1) * 64;
    const int pid = blockIdx.x - 128;

    // ---- phase 1: 24 gi tiles (bm-major) ----
    for (int kt2 = 0; kt2 < 24; ++kt2) {
      const int tile = pid + (kt2 << 7);
      const int bm = tile / 48, bn = tile % 48;
      const __hip_bfloat16* A = g_c_bf    + (size_t)bm * 128 * HH;
      const __hip_bfloat16* B = g_wihc_bf + (size_t)bn * 128 * HH;

      short8 ra[4], rb[4];
#define PG_LOAD(KT, AP, BP, STR) { _Pragma("unroll") for (int q = 0; q < 4; ++q) { \
    int cch = q * 256 + tid; int row = cch >> 3, ko = (cch & 7) * 8; \
    ra[q] = *(const short8*)((AP) + (size_t)row * (STR) + (KT) * 64 + ko); \
    rb[q] = *(const short8*)((BP) + (size_t)row * (STR) + (KT) * 64 + ko); } }
#define PG_STORE(BUF) { _Pragma("unroll") for (int q = 0; q < 4; ++q) { \
    int cch = q * 256 + tid; int row = cch >> 3, ko = (cch & 7) * 8; \
    *(short8*)(AsD + (BUF) * 9216 + row * 72 + ko) = ra[q]; \
    *(short8*)(BsD + (BUF) * 9216 + row * 72 + ko) = rb[q]; } }
#define PG_MMA(BUF) { _Pragma("unroll") for (int ks = 0; ks < 2; ++ks) { \
      short8 a[4], b[4]; \
      _Pragma("unroll") for (int fr = 0; fr < 4; ++fr) \
        a[fr] = *(const short8*)(AsD + (BUF) * 9216 + (roff + fr * 16 + (l & 15)) * 72 + ks * 32 + (l >> 4) * 8); \
      _Pragma("unroll") for (int fc = 0; fc < 4; ++fc) \
        b[fc] = *(const short8*)(BsD + (BUF) * 9216 + (coff + fc * 16 + (l & 15)) * 72 + ks * 32 + (l >> 4) * 8); \
      _Pragma("unroll") for (int fr = 0; fr < 4; ++fr) \
        _Pragma("unroll") for (int fc = 0; fc < 4; ++fc) \
          acc[fr][fc] = __builtin_amdgcn_mfma_f32_16x16x32_bf16(a[fr], b[fc], acc[fr][fc], 0, 0, 0); } }

      __syncthreads();
      PG_LOAD(0, A, B, HH) PG_STORE(0)
      f32x4 acc[4][4] = {};
      for (int kt = 0; kt < 16; ++kt) {
        __syncthreads();
        if (kt < 15) PG_LOAD(kt + 1, A, B, HH)
        PG_MMA(kt & 1)
        if (kt < 15) PG_STORE((kt + 1) & 1)
      }
#pragma unroll
      for (int fr = 0; fr < 4; ++fr)
#pragma unroll
        for (int fc = 0; fc < 4; ++fc) {
          int colg = bn * 128 + coff + fc * 16 + (l & 15);
          int q2 = colg >> 10;
          int gru2 = (q2 >= 3), gate = q2 - 3 * gru2;
          int hcol = colg & 1023, cb = hcol >> 4, j = hcol & 15;
#pragma unroll
          for (int reg = 0; reg < 4; ++reg) {
            int grow = bm * 128 + roff + fr * 16 + (l >> 4) * 4 + reg;
            int tt2 = grow >> 6, n = grow & 63;
            __hip_atomic_store(
                &g_gi2[((size_t)(gru2 * 64 + cb) * TT + tt2) * GISL + n * 48 + gate * 16 + j],
                acc[fr][fc][reg], __ATOMIC_RELAXED, __HIP_MEMORY_SCOPE_AGENT);
          }
        }
      asm volatile("s_waitcnt vmcnt(0)" ::: "memory");
      __syncthreads();
      if (tid == 0)
        __hip_atomic_fetch_add(&g_gi_cnt[bm], 1u,
                               __ATOMIC_RELAXED, __HIP_MEMORY_SCOPE_AGENT);
    }

    // ---- phase 2: 4 pol_gemm tiles, gated on scan flags ----
    for (int k2 = 0; k2 < 4; ++k2) {
      const int tile = (k2 << 7) + pid;        // 0..511
      const int bm = tile >> 3, bn = tile & 7;
      const unsigned need = (unsigned)(2 * bm + 1);
      {
        unsigned fv;
        do {
          fv = __hip_atomic_load(&g_flagsA[0][l], __ATOMIC_RELAXED,
                                 __HIP_MEMORY_SCOPE_AGENT);
        } while (!__all(fv >= need));
        asm volatile("" ::: "memory");
      }
      const __hip_bfloat16* A = g_pin_all + (size_t)bm * 128 * PK;
      const __hip_bfloat16* B = g_pw1_bf  + (size_t)bn * 128 * PK;

      short8 ra[4], rb[4];
      __syncthreads();
      PG_LOAD(0, A, B, PK) PG_STORE(0)
      f32x4 acc[4][4] = {};
      for (int kt = 0; kt < 17; ++kt) {
        __syncthreads();
        if (kt < 16) PG_LOAD(kt + 1, A, B, PK)
        PG_MMA(kt & 1)
        if (kt < 16) PG_STORE((kt + 1) & 1)
      }
#pragma unroll
      for (int fc = 0; fc < 4; ++fc) {
        int colg = bn * 128 + coff + fc * 16 + (l & 15);
        float b1v = pb1[colg];
#pragma unroll
        for (int fr = 0; fr < 4; ++fr)
#pragma unroll
          for (int reg = 0; reg < 4; ++reg) {
            int row = bm * 128 + roff + fr * 16 + (l >> 4) * 4 + reg;
            __hip_bfloat16 hb = __float2bfloat16(tanhf_(acc[fr][fc][reg] + b1v));
            __hip_atomic_store((unsigned short*)&g_ph_all[(size_t)row * HH + colg],
                               *(unsigned short*)&hb,
                               __ATOMIC_RELAXED, __HIP_MEMORY_SCOPE_AGENT);
          }
      }
      asm volatile("s_waitcnt vmcnt(0)" ::: "memory");
      __syncthreads();
      if (tid == 0)
        __hip_atomic_fetch_add(&g_pol_cnt[bm], 1u,
                               __ATOMIC_RELAXED, __HIP_MEMORY_SCOPE_AGENT);
    }

    // ---- phase 3: pdist chunk (64 rows), gated on pol_cnt ----
    {
      const int r0 = pid * 64;
      const int bm2 = pid >> 1;
      while (__hip_atomic_load(&g_pol_cnt[bm2], __ATOMIC_RELAXED,
                               __HIP_MEMORY_SCOPE_AGENT) < 8u) { }
      asm volatile("" ::: "memory");
      f32x4 pa = {};
      const __hip_bfloat16* PH = g_ph_all + (size_t)(r0 + w * 16 + (l & 15)) * HH;
      const __hip_bfloat16* B  = g_pw2_bf + (size_t)(l & 15) * HH;
#pragma unroll 4
      for (int k32 = 0; k32 < 32; ++k32) {
        short8 a = *(const short8*)(PH + k32 * 32 + (l >> 4) * 8);
        short8 b = *(const short8*)(B  + k32 * 32 + (l >> 4) * 8);
        pa = __builtin_amdgcn_mfma_f32_16x16x32_bf16(a, b, pa, 0, 0, 0);
      }
      int o = l & 15;
      float bb = pb2[o];
#pragma unroll
      for (int reg = 0; reg < 4; ++reg) {
        int row = r0 + w * 16 + (l >> 4) * 4 + reg;
        out[PD_OFF + (size_t)row * AA + o] = pa[reg] + bb;
      }
    }
  }
}

// ---------------- final: hxs output ----------------
__global__ __launch_bounds__(256) void final_kernel(float* __restrict__ out) {
  int f = blockIdx.x * 256 + threadIdx.x;   // < 131072
  int n = f >> 11, j = f & 2047;
  out[HXS_OFF + f] = (j < HH) ? g_h[n * HH + j] : g_pol[n * HH + (j - HH)];
}

extern "C" void kernel_launch(void* const* d_in, const int* in_sizes, int n_in,
                              void* d_out, int out_size, void* d_ws, size_t ws_size,
                              hipStream_t stream) {
  const float* c     = (const float*)d_in[0];
  const float* hxs   = (const float*)d_in[1];
  const float* masks = (const float*)d_in[2];
  const float* act   = (const float*)d_in[3];
  const float* wih_h = (const float*)d_in[4];
  const float* whh_h = (const float*)d_in[5];
  const float* bih_h = (const float*)d_in[6];
  const float* bhh_h = (const float*)d_in[7];
  const float* wih_p = (const float*)d_in[8];
  const float* whh_p = (const float*)d_in[9];
  const float* bih_p = (const float*)d_in[10];
  const float* bhh_p = (const float*)d_in[11];
  const float* pw1   = (const float*)d_in[12];
  const float* pb1   = (const float*)d_in[13];
  const float* pw2   = (const float*)d_in[14];
  const float* pb2   = (const float*)d_in[15];
  float* out = (float*)d_out;

  const int dyn_bytes = 48 * WLDS_STRIDE * 2;   // 99072 (>= gemm's 73728)
  (void)hipFuncSetAttribute((const void*)fused_scan,
                            hipFuncAttributeMaxDynamicSharedMemorySize, dyn_bytes);

  conv_all<<<4096, 256, 0, stream>>>(c, masks, act, wih_h, wih_p, pw1, pw2);
  init_kernel<<<256, 256, 0, stream>>>(hxs, masks);
  fused_scan<<<256, 256, dyn_bytes, stream>>>(masks, whh_h, whh_p,
                                              bih_h, bhh_h, bih_p, bhh_p,
                                              pb1, pb2, out);
  final_kernel<<<512, 256, 0, stream>>>(out);
}